// Round 1
// 166.977 us; speedup vs baseline: 1.0332x; 1.0332x over previous
//
#include <hip/hip_runtime.h>
#include <math.h>

#define N_NODES 100000
#define N_EDGES 1600000
#define C_IN    128
#define H_DIM   64
#define G_GRAPHS 512
#define MAXG    4096      // max nodes/graph in kA4 LDS (mean 195, huge margin)
#define ELCAP   65536     // both-kept edge list cap (expected ~tens)
#define KPG     32        // kept-per-graph cap (math bound: scores sum to 1, thresh 0.05 -> <=19)
#define NBITS   3136      // ceil(N/32) rounded up

// ---------- raw = x . pool_w (pure BW) + zero bits/elcount + graph boundaries ----------
__global__ void kpre(const float* __restrict__ x, const float* __restrict__ pool_w,
                     const int* __restrict__ batch,
                     float* __restrict__ sc, unsigned int* __restrict__ zero_region,
                     int* __restrict__ gstart) {
    int gid = blockIdx.x * blockDim.x + threadIdx.x;
    int nthr = gridDim.x * blockDim.x;
    if (gid < NBITS + 1) zero_region[gid] = 0u;   // kept_bits + elcount
    // graph boundary detection (batch sorted): gstart[g] = first node of graph g
    for (int i = gid; i < N_NODES; i += nthr) {
        int b = batch[i];
        int prev = (i == 0) ? -1 : batch[i - 1];
        for (int g = prev + 1; g <= b; ++g) gstart[g] = i;
    }
    if (gid == 0) {
        int last = batch[N_NODES - 1];
        for (int g = last + 1; g <= G_GRAPHS; ++g) gstart[g] = N_NODES;
    }
    const int lane = threadIdx.x & 63;
    const int l32  = lane & 31;
    const int half = lane >> 5;
    const float4 pwv = ((const float4*)pool_w)[l32];
    const int wid = blockIdx.x * (blockDim.x >> 6) + (threadIdx.x >> 6);
    const int nw  = gridDim.x * (blockDim.x >> 6);
    // unroll x2: two row-pairs in flight per iteration (N divisible by 4)
    for (int r0 = wid * 4; r0 < N_NODES; r0 += nw * 4) {
        int rowA = r0 + half;
        int rowB = r0 + 2 + half;
        float4 xa = ((const float4*)(x + (size_t)rowA * C_IN))[l32];
        float4 xb = ((const float4*)(x + (size_t)rowB * C_IN))[l32];
        float pa = xa.x * pwv.x + xa.y * pwv.y + xa.z * pwv.z + xa.w * pwv.w;
        float pb = xb.x * pwv.x + xb.y * pwv.y + xb.z * pwv.z + xb.w * pwv.w;
        #pragma unroll
        for (int m = 16; m > 0; m >>= 1) {
            pa += __shfl_xor(pa, m, 64);
            pb += __shfl_xor(pb, m, 64);
        }
        if (l32 == 0) { sc[rowA] = pa; sc[rowB] = pb; }
    }
}

// block reductions for 256-thread (4-wave) blocks, shuffle + 4-slot LDS
__device__ __forceinline__ float blk_max(float v, float* red, int lane, int w) {
    #pragma unroll
    for (int m = 32; m > 0; m >>= 1) v = fmaxf(v, __shfl_xor(v, m, 64));
    if (lane == 0) red[w] = v;
    __syncthreads();
    float r = fmaxf(fmaxf(red[0], red[1]), fmaxf(red[2], red[3]));
    __syncthreads();
    return r;
}
__device__ __forceinline__ float blk_sum(float v, float* red, int lane, int w) {
    #pragma unroll
    for (int m = 32; m > 0; m >>= 1) v += __shfl_xor(v, m, 64);
    if (lane == 0) red[w] = v;
    __syncthreads();
    float r = (red[0] + red[1]) + (red[2] + red[3]);
    __syncthreads();
    return r;
}

// ---------- per-graph softmax + mask + KL + compaction (gstart: no binary search) ----------
__global__ void kA4(const int* __restrict__ gstart, const float* __restrict__ attn,
                    float* __restrict__ sc, unsigned int* __restrict__ kept_bits,
                    int* __restrict__ klist, int* __restrict__ kcnt,
                    float* __restrict__ B, float* __restrict__ out) {
    __shared__ float buf[MAXG];
    __shared__ float red[4];
    __shared__ int   lst[KPG];
    __shared__ int   cntk;
    const int g = blockIdx.x;
    const int t = threadIdx.x;
    const int lane = t & 63;
    const int w = t >> 6;
    const int ns = gstart[g];
    const int ne = gstart[g + 1];
    const int cn = ne - ns;
    if (cn <= 0) {
        if (t == 0) { out[G_GRAPHS + g] = 0.f; kcnt[g] = 0; }
        return;
    }
    if (t == 0) cntk = 0;
    float lmax = -3.4e38f;
    for (int i = t; i < cn; i += 256) { float r = sc[ns + i]; buf[i] = r; lmax = fmaxf(lmax, r); }
    float m = blk_max(lmax, red, lane, w);
    float lsum = 0.f;
    for (int i = t; i < cn; i += 256) { float e = expf(buf[i] - m); buf[i] = e; lsum += e; }
    float z = blk_sum(lsum, red, lane, w);
    // smax = exp(m - m)/z = 1/z exactly (same rounding as reference's max(e)/z)
    float thresh = fminf(1.f / z - 1e-7f, 0.05f);
    // kept compaction + KL
    float klacc = 0.f;
    for (int i = t; i < cn; i += 256) {
        float s = buf[i] / z;
        if (s > thresh) {
            int n = ns + i;
            int p = atomicAdd(&cntk, 1);
            if (p < KPG) lst[p] = i;
            sc[n] = s;
            float a = attn[n];
            klacc += a * (logf(a) - logf(s + 1e-14f));
        }
    }
    float klsum = blk_sum(klacc, red, lane, w);   // syncs also make cntk/lst visible
    int kct = cntk;
    int kc = kct < KPG ? kct : KPG;
    if (t == 0) {
        out[G_GRAPHS + g] = (kct > 0) ? klsum / (float)kct : 0.f;
        kcnt[g] = kc;
    }
    for (int i = t; i < kc; i += 256) {
        int n = ns + lst[i];
        klist[g * KPG + i] = n;
        atomicOr(&kept_bits[n >> 5], 1u << (n & 31));
    }
    for (int j = t; j < kc * H_DIM; j += 256)
        B[(size_t)(ns + lst[j >> 6]) * H_DIM + (j & 63)] = 0.f;
}

// wave-ballot list emit: one global atomic per wave-with-hits (rare both-kept edges only)
__device__ __forceinline__ void emit(bool hit, int s, int d, int* __restrict__ list,
                                     int cap, int* __restrict__ count, int lane) {
    unsigned long long bal = __ballot(hit);
    if (bal == 0ull) return;
    int leader = __ffsll((long long)bal) - 1;
    int cnt = __popcll(bal);
    int base = 0;
    if (lane == leader) base = atomicAdd(count, cnt);
    base = __shfl(base, leader, 64);
    if (hit) {
        int p = base + __popcll(bal & ((1ull << lane) - 1ull));
        if (p < cap) { list[p] = s; list[cap + p] = d; }
    }
}

// ---------- fused edge scan + layer-1 agg: no W1 LDS staging (W1 is L1/L2-hot) ----------
__global__ void kscan(const int* __restrict__ ei, const unsigned int* __restrict__ bits,
                      const float* __restrict__ x, const float* __restrict__ W1,
                      float* __restrict__ B, int* __restrict__ elsd,
                      int* __restrict__ elcount) {
    __shared__ int ls[1024], ld[1024];    // 8 KB only -> high occupancy
    __shared__ int c1;
    const int t = threadIdx.x;
    const int lane = t & 63;
    if (t == 0) c1 = 0;
    int t4 = blockIdx.x * 256 + t;
    bool valid = t4 < (N_EDGES / 4);
    int4 s4 = make_int4(0, 0, 0, 0), d4 = make_int4(0, 0, 0, 0);
    if (valid) {
        s4 = ((const int4*)ei)[t4];
        d4 = ((const int4*)(ei + N_EDGES))[t4];
    }
    __syncthreads();  // c1 = 0 visible
    int sv[4] = {s4.x, s4.y, s4.z, s4.w};
    int dv[4] = {d4.x, d4.y, d4.z, d4.w};
    bool bk[4];
    #pragma unroll
    for (int q = 0; q < 4; ++q) {
        int ss = sv[q], dd = dv[q];
        bool kd = valid && (((bits[dd >> 5] >> (dd & 31)) & 1u) != 0u);
        bk[q] = kd && (((bits[ss >> 5] >> (ss & 31)) & 1u) != 0u);
        if (kd) { int p = atomicAdd(&c1, 1); ls[p] = ss; ld[p] = dd; }
    }
    #pragma unroll
    for (int q = 0; q < 4; ++q) emit(bk[q], sv[q], dv[q], elsd, ELCAP, elcount, lane);
    __syncthreads();
    const int nloc = c1;
    if (nloc == 0) return;
    const int w = t >> 6;
    for (int idx = w; idx < nloc; idx += 4) {
        int s = ls[idx];
        int d = ld[idx];
        const float4* xr = (const float4*)(x + (size_t)s * C_IN);
        float acc = 0.f;
        #pragma unroll 8
        for (int k4 = 0; k4 < C_IN / 4; ++k4) {
            float4 xv = xr[k4];
            acc = fmaf(xv.x, W1[(4 * k4 + 0) * H_DIM + lane], acc);
            acc = fmaf(xv.y, W1[(4 * k4 + 1) * H_DIM + lane], acc);
            acc = fmaf(xv.z, W1[(4 * k4 + 2) * H_DIM + lane], acc);
            acc = fmaf(xv.w, W1[(4 * k4 + 3) * H_DIM + lane], acc);
        }
        atomicAdd(&B[(size_t)d * H_DIM + lane], acc);
    }
}

// compute channel `lane` of A[n] = score[n] * (relu(relu(x[n]@W1 + B[n] + b1)@W2 + b2)@W3)
// wave-uniform n; must be called by all 64 lanes.
__device__ __forceinline__ float computeA(int n, int lane,
                                          const float* __restrict__ x,
                                          const float* __restrict__ B,
                                          const float* __restrict__ sc,
                                          const float* __restrict__ W1, float b1l,
                                          const float* __restrict__ W2, float b2l,
                                          const float* __restrict__ W3) {
    const float4* xr = (const float4*)(x + (size_t)n * C_IN);
    float u = 0.f;
    #pragma unroll 8
    for (int k4 = 0; k4 < C_IN / 4; ++k4) {
        float4 xv = xr[k4];
        u = fmaf(xv.x, W1[(4 * k4 + 0) * H_DIM + lane], u);
        u = fmaf(xv.y, W1[(4 * k4 + 1) * H_DIM + lane], u);
        u = fmaf(xv.z, W1[(4 * k4 + 2) * H_DIM + lane], u);
        u = fmaf(xv.w, W1[(4 * k4 + 3) * H_DIM + lane], u);
    }
    float t1 = fmaxf(u + B[(size_t)n * H_DIM + lane] + b1l, 0.f);
    float o1 = b2l;
    #pragma unroll 8
    for (int k = 0; k < H_DIM; ++k) o1 = fmaf(__shfl(t1, k, 64), W2[k * H_DIM + lane], o1);
    o1 = fmaxf(o1, 0.f);
    float v = 0.f;
    #pragma unroll 8
    for (int k = 0; k < H_DIM; ++k) v = fmaf(__shfl(o1, k, 64), W3[k * H_DIM + lane], v);
    return v * sc[n];
}

// ---------- parallel A-computation: one computeA per kept node across 2048 waves.
// Slot order (i*G + g) load-balances: wave's slots span all i for one g -> <=~1 hit/wave.
// Overwrites B[n] (layer-1 agg, no longer needed) with A[n].
__global__ void kAcomp(const int* __restrict__ klist, const int* __restrict__ kcnt,
                       const float* __restrict__ sc, const float* __restrict__ x,
                       const float* __restrict__ W1, const float* __restrict__ b1,
                       const float* __restrict__ W2, const float* __restrict__ b2,
                       const float* __restrict__ W3, float* __restrict__ B) {
    const int lane = threadIdx.x & 63;
    const float b1l = b1[lane], b2l = b2[lane];
    const int gw = blockIdx.x * (blockDim.x >> 6) + (threadIdx.x >> 6);
    const int nw = gridDim.x * (blockDim.x >> 6);
    for (int sl = gw; sl < G_GRAPHS * KPG; sl += nw) {
        const int i = sl >> 9;              // sl / G_GRAPHS
        const int g = sl & (G_GRAPHS - 1);  // sl % G_GRAPHS
        if (i < kcnt[g]) {
            int n = __builtin_amdgcn_readfirstlane(klist[g * KPG + i]);
            float a = computeA(n, lane, x, B, sc, W1, b1l, W2, b2l, W3);
            B[(size_t)n * H_DIM + lane] = a;
        }
    }
}

// ---------- per-graph finisher: A-vectors are precomputed -> loads only.
// One elsd scan per graph (not per node); W4 chain + pool + pred + ratio.
__global__ void k8f(const int* __restrict__ klist, const int* __restrict__ kcnt,
                    const float* __restrict__ B,
                    const float* __restrict__ b3, const float* __restrict__ W4,
                    const float* __restrict__ b4, const float* __restrict__ Wl,
                    const float* __restrict__ bl, const int* __restrict__ elsd,
                    const int* __restrict__ elcount, float* __restrict__ out) {
    __shared__ float agg[KPG][H_DIM];
    __shared__ int kl_s[KPG];
    const int g = blockIdx.x;
    const int lane = threadIdx.x;  // 64 threads
    const float b3l = b3[lane], b4l = b4[lane];
    const int kc = kcnt[g];
    if (lane < kc) kl_s[lane] = klist[g * KPG + lane];
    for (int i = 0; i < kc; ++i) agg[i][lane] = 0.f;
    __syncthreads();  // kl_s visible across the wave
    int ec = *elcount; if (ec > ELCAP) ec = ELCAP;
    for (int base = 0; base < ec; base += 64) {
        int idx = base + lane;
        int d = (idx < ec) ? elsd[ELCAP + idx] : -1;
        int pos = -1;
        for (int i = 0; i < kc; ++i) if (kl_s[i] == d) pos = i;  // kc wave-uniform
        int s = (pos >= 0) ? elsd[idx] : 0;
        unsigned long long bal = __ballot(pos >= 0);
        while (bal) {
            int j = __ffsll((long long)bal) - 1;
            bal &= bal - 1;
            int su = __builtin_amdgcn_readfirstlane(__shfl(s, j, 64));
            int pu = __builtin_amdgcn_readfirstlane(__shfl(pos, j, 64));
            agg[pu][lane] += B[(size_t)su * H_DIM + lane];  // lane-local column
        }
    }
    float gsum = 0.f;
    for (int i = 0; i < kc; ++i) {
        int n = __builtin_amdgcn_readfirstlane(kl_s[i]);
        float t = fmaxf(B[(size_t)n * H_DIM + lane] + agg[i][lane] + b3l, 0.f);
        float o2 = b4l;
        #pragma unroll 8
        for (int k = 0; k < H_DIM; ++k) o2 = fmaf(__shfl(t, k, 64), W4[k * H_DIM + lane], o2);
        gsum += fmaxf(o2, 0.f);
    }
    float p = gsum * Wl[lane];
    #pragma unroll
    for (int m = 32; m > 0; m >>= 1) p += __shfl_xor(p, m, 64);
    if (lane == 0) out[g] = p + bl[0];
    if (g == 0) {
        int tot = 0;
        for (int i = lane; i < G_GRAPHS; i += 64) tot += kcnt[i];
        #pragma unroll
        for (int m = 32; m > 0; m >>= 1) tot += __shfl_xor(tot, m, 64);
        if (lane == 0) out[2 * G_GRAPHS] = (float)tot * (1.f / (float)N_NODES);
    }
}

extern "C" void kernel_launch(void* const* d_in, const int* in_sizes, int n_in,
                              void* d_out, int out_size, void* d_ws, size_t ws_size,
                              hipStream_t stream) {
    const float* x      = (const float*)d_in[0];
    const int*   ei     = (const int*)d_in[1];
    const int*   batch  = (const int*)d_in[2];
    const float* attn   = (const float*)d_in[3];
    const float* W1     = (const float*)d_in[4];
    const float* b1     = (const float*)d_in[5];
    const float* W2     = (const float*)d_in[6];
    const float* b2     = (const float*)d_in[7];
    const float* pool_w = (const float*)d_in[8];
    const float* W3     = (const float*)d_in[9];
    const float* b3     = (const float*)d_in[10];
    const float* W4     = (const float*)d_in[11];
    const float* b4     = (const float*)d_in[12];
    const float* Wl     = (const float*)d_in[13];
    const float* bl     = (const float*)d_in[14];
    float* out = (float*)d_out;

    // workspace layout
    float* B      = (float*)d_ws;                       // N*64 (kept rows: agg1 -> A)
    float* sc     = B + (size_t)N_NODES * H_DIM;        // N: raw -> kept scores
    int*   klist  = (int*)(sc + N_NODES);               // G*KPG (per-graph strided)
    int*   kcnt   = klist + G_GRAPHS * KPG;             // G
    int*   elsd   = kcnt + G_GRAPHS;                    // 2*ELCAP
    unsigned int* kept_bits = (unsigned int*)(elsd + 2 * ELCAP);   // NBITS
    int*          elcount   = (int*)(kept_bits + NBITS);           // 1 (zeroed with bits)
    int*          gstart    = elcount + 1;                         // G+1

    kpre  <<<2048, 256, 0, stream>>>(x, pool_w, batch, sc, kept_bits, gstart);
    kA4   <<<G_GRAPHS, 256, 0, stream>>>(gstart, attn, sc, kept_bits, klist, kcnt, B, out);
    kscan <<<(N_EDGES / 4 + 255) / 256, 256, 0, stream>>>(ei, kept_bits, x, W1, B,
                                                          elsd, elcount);
    kAcomp<<<512, 256, 0, stream>>>(klist, kcnt, sc, x, W1, b1, W2, b2, W3, B);
    k8f   <<<G_GRAPHS, 64, 0, stream>>>(klist, kcnt, B, b3, W4, b4, Wl, bl,
                                        elsd, elcount, out);
}